// Round 13
// baseline (47.171 us; speedup 1.0000x reference)
//
#include <hip/hip_runtime.h>

typedef short s16x8 __attribute__((ext_vector_type(8)));
typedef float f32x4 __attribute__((ext_vector_type(4)));
typedef unsigned short u16;

#define BATCH 512
#define HD    1023
#define K0    2048
#define N0    2048
#define N1    1024
#define N2    512

// round-to-nearest-even f32 -> bf16 (scalar path)
__device__ __forceinline__ u16 f2bf(float f) {
  unsigned u = __builtin_bit_cast(unsigned, f);
  unsigned r = (u + 0x7fffu + ((u >> 16) & 1u)) >> 16;
  return (u16)r;
}

// packed RNE convert: 8 f32 -> 8 bf16 in 4 VALU ops
__device__ __forceinline__ s16x8 pack8(f32x4 a, f32x4 b) {
  union { unsigned u[4]; s16x8 v; } r;
  asm("v_cvt_pk_bf16_f32 %0, %1, %2" : "=v"(r.u[0]) : "v"(a[0]), "v"(a[1]));
  asm("v_cvt_pk_bf16_f32 %0, %1, %2" : "=v"(r.u[1]) : "v"(a[2]), "v"(a[3]));
  asm("v_cvt_pk_bf16_f32 %0, %1, %2" : "=v"(r.u[2]) : "v"(b[0]), "v"(b[1]));
  asm("v_cvt_pk_bf16_f32 %0, %1, %2" : "=v"(r.u[3]) : "v"(b[2]), "v"(b[3]));
  return r.v;
}

// 16B load from 4B-aligned source
__device__ __forceinline__ f32x4 ld4u(const float* p) {
  f32x4 v; __builtin_memcpy(&v, p, 16); return v;
}

// ================= K0: prep — gather x (vectorized), convert W0, init out ========
__global__ __launch_bounds__(256) void k_prep(
    const int* __restrict__ pairs, const float* __restrict__ attrs,
    const float* __restrict__ h_drug, const float* __restrict__ W0,
    const int* __restrict__ cells, const float* __restrict__ O1,
    u16* __restrict__ xb, u16* __restrict__ w0b, float* __restrict__ out) {
  const int bid = blockIdx.x, tid = threadIdx.x;
  if (bid < 512) {
    const int b = bid;
    const int half = tid >> 7, ch = tid & 127;     // 2 halves x 128 chunks of 8
    const float* h = h_drug + (size_t)pairs[2 * b + half] * HD;
    u16* xr = xb + (size_t)b * K0 + half * 1024;
    f32x4 v0, v1;
    if (ch < 127) {
      v0 = ld4u(h + ch * 8);
      v1 = ld4u(h + ch * 8 + 4);
    } else {  // elems 1016..1022 + attr scalar
      v0 = ld4u(h + 1016);
      v1[0] = h[1020]; v1[1] = h[1021]; v1[2] = h[1022];
      v1[3] = attrs[4 * b + 1 + 2 * half];
    }
    *(s16x8*)(xr + ch * 8) = pack8(v0, v1);
    if (tid == 0) out[b] = O1[cells[b]];
  } else {
    const size_t e = ((size_t)(bid - 512) * 256 + tid) * 16;
    f32x4 a = *(const f32x4*)(W0 + e),     b2 = *(const f32x4*)(W0 + e + 4);
    f32x4 c = *(const f32x4*)(W0 + e + 8), d  = *(const f32x4*)(W0 + e + 12);
    *(s16x8*)(w0b + e)     = pack8(a, b2);
    *(s16x8*)(w0b + e + 8) = pack8(c, d);
  }
}

// ================= K1: gemm1 — 64x64 tile, BK=256, 8 waves, grid 256 + W1 riders ==
// y1 = relu(X * W0^T + b0), all bf16 operands. NT=8, 2-deep reg prefetch,
// 512B-row LDS with XOR swizzle byte^=(row&15)<<4, raw s_barrier+lgkmcnt(0) (T4), T5.
#define GI1(s, t) { \
  pa0_##s = *(const s16x8*)(agp0 + (size_t)(t) * 512); \
  pa1_##s = *(const s16x8*)(agp1 + (size_t)(t) * 512); \
  pa2_##s = *(const s16x8*)(agp2 + (size_t)(t) * 512); \
  pa3_##s = *(const s16x8*)(agp3 + (size_t)(t) * 512); \
  pb0_##s = *(const s16x8*)(bgp0 + (size_t)(t) * 512); \
  pb1_##s = *(const s16x8*)(bgp1 + (size_t)(t) * 512); \
  pb2_##s = *(const s16x8*)(bgp2 + (size_t)(t) * 512); \
  pb3_##s = *(const s16x8*)(bgp3 + (size_t)(t) * 512); }

#define GS1(s, t, DOLOAD) { \
  char* buf = lds[(s) & 1]; \
  *(s16x8*)(buf + awo0) = pa0_##s; \
  *(s16x8*)(buf + awo1) = pa1_##s; \
  *(s16x8*)(buf + awo2) = pa2_##s; \
  *(s16x8*)(buf + awo3) = pa3_##s; \
  *(s16x8*)(buf + 32768 + awo0) = pb0_##s; \
  *(s16x8*)(buf + 32768 + awo1) = pb1_##s; \
  *(s16x8*)(buf + 32768 + awo2) = pb2_##s; \
  *(s16x8*)(buf + 32768 + awo3) = pb3_##s; \
  asm volatile("s_waitcnt lgkmcnt(0)" ::: "memory"); \
  __builtin_amdgcn_s_barrier(); \
  asm volatile("" ::: "memory"); \
  if (DOLOAD) GI1(s, (t) + 2) \
  __builtin_amdgcn_s_setprio(1); \
  _Pragma("unroll") \
  for (int ks = 0; ks < 8; ++ks) { \
    const int kq = ((ks << 6) | lk) ^ swz; \
    s16x8 a0 = *(const s16x8*)(buf + aoff + kq); \
    s16x8 a1 = *(const s16x8*)(buf + aoff + 8192 + kq); \
    s16x8 b0 = *(const s16x8*)(buf + 32768 + boff + kq); \
    acc0 = __builtin_amdgcn_mfma_f32_16x16x32_bf16(a0, b0, acc0, 0, 0, 0); \
    acc1 = __builtin_amdgcn_mfma_f32_16x16x32_bf16(a1, b0, acc1, 0, 0, 0); \
  } \
  __builtin_amdgcn_s_setprio(0); }

__global__ __launch_bounds__(512) void k_gemm1(
    const u16* __restrict__ A, const u16* __restrict__ B,
    const float* __restrict__ bias, u16* __restrict__ Y,
    const float* __restrict__ W1f, u16* __restrict__ w1b) {
  constexpr int K = 2048, N = 2048;
  if (blockIdx.x >= 256) {  // W1 conversion riders
    const size_t e = (((size_t)blockIdx.x - 256) * 512 + threadIdx.x) * 8;
    f32x4 a = *(const f32x4*)(W1f + e), b2 = *(const f32x4*)(W1f + e + 4);
    *(s16x8*)(w1b + e) = pack8(a, b2);
    return;
  }
  __shared__ char lds[2][65536];  // A 32KB + B 32KB per buffer (128 KB total)
  const int tid = threadIdx.x;
  const int w = tid >> 6, l = tid & 63;
  const int wr = w >> 2, wn = w & 3;
  const int lrow = l & 15;
  const int lk = (l >> 4) << 4;
  const int swz = lrow << 4;

  // XCD swizzle (256 GEMM blocks): each XCD owns 32 contiguous wgids (4 bn x 8 bm)
  const int wgid = (blockIdx.x & 7) * 32 + (blockIdx.x >> 3);
  const int bn = wgid >> 3, bm = wgid & 7;

  const size_t K2 = (size_t)K * 2;  // 4096 B/row
  const char* Ag = (const char*)A + (size_t)bm * 64 * K2;
  const char* Bg = (const char*)B + (size_t)bn * 64 * K2;

  // staging: tile 64 rows x 512B; thread covers 4 slots at tid*16 + i*8192
  const int arow = tid >> 5;            // 0..15 (slot i adds 16 rows)
  const int acol = (tid & 31) * 16;     // 0..496
  const int ar0 = arow, ar1 = arow + 16, ar2 = arow + 32, ar3 = arow + 48;
  const char* agp0 = Ag + (size_t)ar0 * K2 + acol;
  const char* agp1 = Ag + (size_t)ar1 * K2 + acol;
  const char* agp2 = Ag + (size_t)ar2 * K2 + acol;
  const char* agp3 = Ag + (size_t)ar3 * K2 + acol;
  const char* bgp0 = Bg + (size_t)ar0 * K2 + acol;
  const char* bgp1 = Bg + (size_t)ar1 * K2 + acol;
  const char* bgp2 = Bg + (size_t)ar2 * K2 + acol;
  const char* bgp3 = Bg + (size_t)ar3 * K2 + acol;
  const int awo0 = (ar0 << 9) + (acol ^ ((ar0 & 15) << 4));
  const int awo1 = (ar1 << 9) + (acol ^ ((ar1 & 15) << 4));
  const int awo2 = (ar2 << 9) + (acol ^ ((ar2 & 15) << 4));
  const int awo3 = (ar3 << 9) + (acol ^ ((ar3 & 15) << 4));

  const int aoff = (wr * 32 + lrow) * 512;
  const int boff = (wn * 16 + lrow) * 512;

  f32x4 acc0 = {}, acc1 = {};
  s16x8 pa0_0, pa1_0, pa2_0, pa3_0, pb0_0, pb1_0, pb2_0, pb3_0;
  s16x8 pa0_1, pa1_1, pa2_1, pa3_1, pb0_1, pb1_1, pb2_1, pb3_1;

  GI1(0, 0) GI1(1, 1)
  constexpr int NT = 8;  // K/256
  int t = 0;
  for (; t < NT - 2; t += 2) {
    GS1(0, t, 1) GS1(1, t + 1, 1)
  }
  GS1(0, t, 0) GS1(1, t + 1, 0)

  // epilogue: C/D map col=lane&15, row=(lane>>4)*4+reg
  const int colg = bn * 64 + wn * 16 + lrow;
  const int rowb = bm * 64 + wr * 32 + ((l >> 4) << 2);
  const float bv = bias[colg];
#pragma unroll
  for (int fa = 0; fa < 2; ++fa)
#pragma unroll
    for (int r = 0; r < 4; ++r) {
      float v = (fa ? acc1 : acc0)[r] + bv;
      v = v > 0.f ? v : 0.f;
      Y[(size_t)(rowb + fa * 16 + r) * N + colg] = f2bf(v);
    }
}

// ================= K2: gemm2 — 32x64 tile, BK=256, 8 waves, grid 256 ============
#define GI2(s, t) { \
  pa0_##s = *(const s16x8*)(agp0 + (size_t)(t) * 512); \
  pa1_##s = *(const s16x8*)(agp1 + (size_t)(t) * 512); \
  pb0_##s = *(const s16x8*)(bgp0 + (size_t)(t) * 512); \
  pb1_##s = *(const s16x8*)(bgp1 + (size_t)(t) * 512); \
  pb2_##s = *(const s16x8*)(bgp2 + (size_t)(t) * 512); \
  pb3_##s = *(const s16x8*)(bgp3 + (size_t)(t) * 512); }

#define GS2(s, t, DOLOAD) { \
  char* buf = lds[(s) & 1]; \
  *(s16x8*)(buf + awo0) = pa0_##s; \
  *(s16x8*)(buf + awo1) = pa1_##s; \
  *(s16x8*)(buf + 16384 + bwo0) = pb0_##s; \
  *(s16x8*)(buf + 16384 + bwo1) = pb1_##s; \
  *(s16x8*)(buf + 16384 + bwo2) = pb2_##s; \
  *(s16x8*)(buf + 16384 + bwo3) = pb3_##s; \
  asm volatile("s_waitcnt lgkmcnt(0)" ::: "memory"); \
  __builtin_amdgcn_s_barrier(); \
  asm volatile("" ::: "memory"); \
  if (DOLOAD) GI2(s, (t) + 2) \
  __builtin_amdgcn_s_setprio(1); \
  _Pragma("unroll") \
  for (int ks = 0; ks < 8; ++ks) { \
    const int kq = ((ks << 6) | lk) ^ swz; \
    s16x8 a0 = *(const s16x8*)(buf + aoff + kq); \
    s16x8 b0 = *(const s16x8*)(buf + 16384 + boff + kq); \
    acc0 = __builtin_amdgcn_mfma_f32_16x16x32_bf16(a0, b0, acc0, 0, 0, 0); \
  } \
  __builtin_amdgcn_s_setprio(0); }

__global__ __launch_bounds__(512) void k_gemm2(
    const u16* __restrict__ A, const u16* __restrict__ B,
    const float* __restrict__ bias, u16* __restrict__ Y) {
  constexpr int K = 2048, N = 1024;
  __shared__ char lds[2][49152];  // A 16KB + B 32KB per buffer (96 KB total)
  const int tid = threadIdx.x;
  const int w = tid >> 6, l = tid & 63;
  const int wr = w >> 2, wn = w & 3;
  const int lrow = l & 15;
  const int lk = (l >> 4) << 4;
  const int swz = lrow << 4;

  // XCD swizzle (grid 256): each XCD owns 32 contiguous wgids (2 bn x 16 bm)
  const int wgid = (blockIdx.x & 7) * 32 + (blockIdx.x >> 3);
  const int bn = wgid >> 4, bm = wgid & 15;

  const size_t K2 = (size_t)K * 2;
  const char* Ag = (const char*)A + (size_t)bm * 32 * K2;
  const char* Bg = (const char*)B + (size_t)bn * 64 * K2;

  const int arow = tid >> 5;            // 0..15
  const int acol = (tid & 31) * 16;
  const int ar0 = arow, ar1 = arow + 16, ar2 = arow + 32, ar3 = arow + 48;
  // A: 32 rows x 512B = 16KB; 2 slots/thread
  const char* agp0 = Ag + (size_t)ar0 * K2 + acol;
  const char* agp1 = Ag + (size_t)ar1 * K2 + acol;
  const int awo0 = (ar0 << 9) + (acol ^ ((ar0 & 15) << 4));
  const int awo1 = (ar1 << 9) + (acol ^ ((ar1 & 15) << 4));
  // B: 64 rows x 512B = 32KB; 4 slots/thread
  const char* bgp0 = Bg + (size_t)ar0 * K2 + acol;
  const char* bgp1 = Bg + (size_t)ar1 * K2 + acol;
  const char* bgp2 = Bg + (size_t)ar2 * K2 + acol;
  const char* bgp3 = Bg + (size_t)ar3 * K2 + acol;
  const int bwo0 = awo0;
  const int bwo1 = awo1;
  const int bwo2 = (ar2 << 9) + (acol ^ ((ar2 & 15) << 4));
  const int bwo3 = (ar3 << 9) + (acol ^ ((ar3 & 15) << 4));

  const int aoff = (wr * 16 + lrow) * 512;
  const int boff = (wn * 16 + lrow) * 512;

  f32x4 acc0 = {};
  s16x8 pa0_0, pa1_0, pb0_0, pb1_0, pb2_0, pb3_0;
  s16x8 pa0_1, pa1_1, pb0_1, pb1_1, pb2_1, pb3_1;

  GI2(0, 0) GI2(1, 1)
  constexpr int NT = 8;
  int t = 0;
  for (; t < NT - 2; t += 2) {
    GS2(0, t, 1) GS2(1, t + 1, 1)
  }
  GS2(0, t, 0) GS2(1, t + 1, 0)

  const int colg = bn * 64 + wn * 16 + lrow;
  const int rowb = bm * 32 + wr * 16 + ((l >> 4) << 2);
  const float bv = bias[colg];
#pragma unroll
  for (int r = 0; r < 4; ++r) {
    float v = acc0[r] + bv;
    v = v > 0.f ? v : 0.f;
    Y[(size_t)(rowb + r) * N + colg] = f2bf(v);
  }
}

// ================= K3: head; atomicAdd partials into out =============
#define H_ISSUE(S, ch) { \
  const float* src = hsrc + (ch) * 256; \
  q0_##S = *(const f32x4*)(src);      q1_##S = *(const f32x4*)(src + 4); \
  q2_##S = *(const f32x4*)(src + 8);  q3_##S = *(const f32x4*)(src + 12); \
  q4_##S = *(const f32x4*)(src + 16); q5_##S = *(const f32x4*)(src + 20); \
  q6_##S = *(const f32x4*)(src + 24); q7_##S = *(const f32x4*)(src + 28); }

#define H_WRITE(S, ch) { \
  char* dst = lbuf[(ch) & 1] + (hrow << 9); \
  *(s16x8*)(dst + ((hcb + 0)  ^ hswz)) = pack8(q0_##S, q1_##S); \
  *(s16x8*)(dst + ((hcb + 16) ^ hswz)) = pack8(q2_##S, q3_##S); \
  *(s16x8*)(dst + ((hcb + 32) ^ hswz)) = pack8(q4_##S, q5_##S); \
  *(s16x8*)(dst + ((hcb + 48) ^ hswz)) = pack8(q6_##S, q7_##S); }

#define H_SYNC { \
  asm volatile("s_waitcnt lgkmcnt(0)" ::: "memory"); \
  __builtin_amdgcn_s_barrier(); \
  asm volatile("" ::: "memory"); }

#define H_MFMA(ch) { \
  const char* bb = lbuf[(ch) & 1]; \
  s16x8 bv0 = *(const s16x8*)(bb + ((0 * 16 + lrow) << 9) + kboff); \
  s16x8 bv1 = *(const s16x8*)(bb + ((1 * 16 + lrow) << 9) + kboff); \
  s16x8 bv2 = *(const s16x8*)(bb + ((2 * 16 + lrow) << 9) + kboff); \
  s16x8 bv3 = *(const s16x8*)(bb + ((3 * 16 + lrow) << 9) + kboff); \
  s16x8 av0 = *(const s16x8*)(ap0 + (ch) * 256); \
  s16x8 av1 = *(const s16x8*)(ap1 + (ch) * 256); \
  __builtin_amdgcn_s_setprio(1); \
  acc[0][0] = __builtin_amdgcn_mfma_f32_16x16x32_bf16(av0, bv0, acc[0][0], 0, 0, 0); \
  acc[0][1] = __builtin_amdgcn_mfma_f32_16x16x32_bf16(av0, bv1, acc[0][1], 0, 0, 0); \
  acc[0][2] = __builtin_amdgcn_mfma_f32_16x16x32_bf16(av0, bv2, acc[0][2], 0, 0, 0); \
  acc[0][3] = __builtin_amdgcn_mfma_f32_16x16x32_bf16(av0, bv3, acc[0][3], 0, 0, 0); \
  acc[1][0] = __builtin_amdgcn_mfma_f32_16x16x32_bf16(av1, bv0, acc[1][0], 0, 0, 0); \
  acc[1][1] = __builtin_amdgcn_mfma_f32_16x16x32_bf16(av1, bv1, acc[1][1], 0, 0, 0); \
  acc[1][2] = __builtin_amdgcn_mfma_f32_16x16x32_bf16(av1, bv2, acc[1][2], 0, 0, 0); \
  acc[1][3] = __builtin_amdgcn_mfma_f32_16x16x32_bf16(av1, bv3, acc[1][3], 0, 0, 0); \
  __builtin_amdgcn_s_setprio(0); }

__global__ __launch_bounds__(512) void k_head(
    const int* __restrict__ cells, const u16* __restrict__ y2b,
    const float* __restrict__ L0, const float* __restrict__ O0,
    const float* __restrict__ L1, float* __restrict__ out) {
  __shared__ int slist[544];
  __shared__ int scnt;
  __shared__ float red[8][2048];      // 64 KB
  __shared__ char lbuf[2][32768];     // 64 KB
  const int tid = threadIdx.x;
  const int c = blockIdx.x >> 3, rt = blockIdx.x & 7;
  if (tid == 0) scnt = 0;
  __syncthreads();
  for (int i = tid; i < BATCH; i += 512)
    if (cells[i] == c) slist[atomicAdd(&scnt, 1)] = i;
  __syncthreads();
  const int ns = scnt;
  if (ns == 0) return;
  const int npad = (ns + 31) & ~31;
  for (int i = ns + tid; i < npad; i += 512) slist[i] = slist[0];
  __syncthreads();

  const int w = tid >> 6, l = tid & 63;
  const int lrow = l & 15;
  const int r0 = rt * 64;
  const float* L0c = L0 + ((size_t)c * N2 + r0) * N1;
  const int hrow = tid >> 3;
  const int hcb = (tid & 7) * 64;
  const int hswz = (hrow & 7) << 4;
  const float* hsrc = L0c + (size_t)hrow * N1 + (tid & 7) * 32;
  const int kboff = ((w * 64 + ((l >> 4) << 4)) ^ ((lrow & 7) << 4));

  f32x4 q0_A, q1_A, q2_A, q3_A, q4_A, q5_A, q6_A, q7_A;
  f32x4 q0_B, q1_B, q2_B, q3_B, q4_B, q5_B, q6_B, q7_B;

  for (int cb = 0; cb < npad; cb += 32) {
    const u16* ap0 = y2b + (size_t)slist[cb + lrow] * N1 + w * 32 + ((l >> 4) << 3);
    const u16* ap1 = y2b + (size_t)slist[cb + 16 + lrow] * N1 + w * 32 + ((l >> 4) << 3);
    f32x4 acc[2][4] = {};
    H_ISSUE(A, 0)
    H_WRITE(A, 0)
    H_ISSUE(B, 1)
    H_SYNC
    H_MFMA(0)
    H_WRITE(B, 1)
    H_ISSUE(A, 2)
    H_SYNC
    H_MFMA(1)
    H_WRITE(A, 2)
    H_ISSUE(B, 3)
    H_SYNC
    H_MFMA(2)
    H_WRITE(B, 3)
    H_SYNC
    H_MFMA(3)

    __syncthreads();
#pragma unroll
    for (int h = 0; h < 2; ++h)
#pragma unroll
      for (int fb = 0; fb < 4; ++fb)
#pragma unroll
        for (int r = 0; r < 4; ++r) {
          const int s0 = h * 16 + (l >> 4) * 4 + r;
          red[w][s0 * 64 + fb * 16 + lrow] = acc[h][fb][r];
        }
    __syncthreads();
    {
      const int s = tid >> 4;
      const int rq = (tid & 15) * 4;
      if (cb + s < ns) {
        float p = 0.f;
#pragma unroll
        for (int j = 0; j < 4; ++j) {
          const int r = rq + j, e = s * 64 + r;
          float v = red[0][e] + red[1][e] + red[2][e] + red[3][e] +
                    red[4][e] + red[5][e] + red[6][e] + red[7][e] +
                    O0[(size_t)c * N2 + r0 + r];
          v = v > 0.f ? v : 0.f;
          p += v * L1[(size_t)c * N2 + r0 + r];
        }
#pragma unroll
        for (int off = 8; off; off >>= 1) p += __shfl_xor(p, off, 16);
        if ((tid & 15) == 0) atomicAdd(&out[slist[cb + s]], p);
      }
    }
  }
}

// ---------------- launch ----------------
extern "C" void kernel_launch(void* const* d_in, const int* in_sizes, int n_in,
                              void* d_out, int out_size, void* d_ws, size_t ws_size,
                              hipStream_t stream) {
  const int*   pairs  = (const int*)d_in[0];
  const int*   cells  = (const int*)d_in[1];
  const float* attrs  = (const float*)d_in[2];
  const float* h_drug = (const float*)d_in[3];
  const float* W0     = (const float*)d_in[4];
  const float* b0     = (const float*)d_in[5];
  const float* W1     = (const float*)d_in[6];
  const float* b1     = (const float*)d_in[7];
  const float* L0     = (const float*)d_in[8];
  const float* O0     = (const float*)d_in[9];
  const float* L1     = (const float*)d_in[10];
  const float* O1     = (const float*)d_in[11];
  float* out = (float*)d_out;

  char* ws = (char*)d_ws;
  u16* xb  = (u16*)(ws);                  // 2 MB  512x2048 bf16
  u16* w0b = (u16*)(ws + (2u  << 20));    // 8 MB  2048x2048 bf16
  u16* w1b = (u16*)(ws + (10u << 20));    // 4 MB  1024x2048 bf16
  u16* y1b = (u16*)(ws + (14u << 20));    // 2 MB  512x2048 bf16
  u16* y2b = (u16*)(ws + (16u << 20));    // 1 MB  512x1024 bf16

  k_prep<<<1536, 256, 0, stream>>>(pairs, attrs, h_drug, W0, cells, O1,
                                   xb, w0b, out);
  k_gemm1<<<768, 512, 0, stream>>>(xb, w0b, b0, y1b, W1, w1b);
  k_gemm2<<<256, 512, 0, stream>>>(y1b, w1b, b1, y2b);
  k_head<<<256, 512, 0, stream>>>(cells, y2b, L0, O0, L1, out);
}

// Round 14
// 45.059 us; speedup vs baseline: 1.0469x; 1.0469x over previous
//
#include <hip/hip_runtime.h>

typedef short s16x8 __attribute__((ext_vector_type(8)));
typedef float f32x4 __attribute__((ext_vector_type(4)));
typedef unsigned short u16;

#define BATCH 512
#define HD    1023
#define K0    2048
#define N0    2048
#define N1    1024
#define N2    512

// round-to-nearest-even f32 -> bf16 (scalar path)
__device__ __forceinline__ u16 f2bf(float f) {
  unsigned u = __builtin_bit_cast(unsigned, f);
  unsigned r = (u + 0x7fffu + ((u >> 16) & 1u)) >> 16;
  return (u16)r;
}

// packed RNE convert: 8 f32 -> 8 bf16 in 4 VALU ops
__device__ __forceinline__ s16x8 pack8(f32x4 a, f32x4 b) {
  union { unsigned u[4]; s16x8 v; } r;
  asm("v_cvt_pk_bf16_f32 %0, %1, %2" : "=v"(r.u[0]) : "v"(a[0]), "v"(a[1]));
  asm("v_cvt_pk_bf16_f32 %0, %1, %2" : "=v"(r.u[1]) : "v"(a[2]), "v"(a[3]));
  asm("v_cvt_pk_bf16_f32 %0, %1, %2" : "=v"(r.u[2]) : "v"(b[0]), "v"(b[1]));
  asm("v_cvt_pk_bf16_f32 %0, %1, %2" : "=v"(r.u[3]) : "v"(b[2]), "v"(b[3]));
  return r.v;
}

// 16B load from 4B-aligned source
__device__ __forceinline__ f32x4 ld4u(const float* p) {
  f32x4 v; __builtin_memcpy(&v, p, 16); return v;
}

// ================= K0: prep — gather x (vectorized), convert W0, init out ========
__global__ __launch_bounds__(256) void k_prep(
    const int* __restrict__ pairs, const float* __restrict__ attrs,
    const float* __restrict__ h_drug, const float* __restrict__ W0,
    const int* __restrict__ cells, const float* __restrict__ O1,
    u16* __restrict__ xb, u16* __restrict__ w0b, float* __restrict__ out) {
  const int bid = blockIdx.x, tid = threadIdx.x;
  if (bid < 512) {
    const int b = bid;
    const int half = tid >> 7, ch = tid & 127;     // 2 halves x 128 chunks of 8
    const float* h = h_drug + (size_t)pairs[2 * b + half] * HD;
    u16* xr = xb + (size_t)b * K0 + half * 1024;
    f32x4 v0, v1;
    if (ch < 127) {
      v0 = ld4u(h + ch * 8);
      v1 = ld4u(h + ch * 8 + 4);
    } else {  // elems 1016..1022 + attr scalar
      v0 = ld4u(h + 1016);
      v1[0] = h[1020]; v1[1] = h[1021]; v1[2] = h[1022];
      v1[3] = attrs[4 * b + 1 + 2 * half];
    }
    *(s16x8*)(xr + ch * 8) = pack8(v0, v1);
    if (tid == 0) out[b] = O1[cells[b]];
  } else {
    const size_t e = ((size_t)(bid - 512) * 256 + tid) * 16;
    f32x4 a = *(const f32x4*)(W0 + e),     b2 = *(const f32x4*)(W0 + e + 4);
    f32x4 c = *(const f32x4*)(W0 + e + 8), d  = *(const f32x4*)(W0 + e + 12);
    *(s16x8*)(w0b + e)     = pack8(a, b2);
    *(s16x8*)(w0b + e + 8) = pack8(c, d);
  }
}

// ================= K1: gemm1 — 64x64 tile, BK=128, 8 waves, grid 256 + W1 riders ==
// y1 = relu(X * W0^T + b0), all bf16 operands. NT=16, 4-deep reg prefetch,
// 256B-row LDS with XOR swizzle byte^=(row&15)<<4, raw s_barrier+lgkmcnt(0) (T4), T5.
#define GI1(s, t) { \
  pa0_##s = *(const s16x8*)(agp0 + (size_t)(t) * 256); \
  pa1_##s = *(const s16x8*)(agp1 + (size_t)(t) * 256); \
  pb0_##s = *(const s16x8*)(bgp0 + (size_t)(t) * 256); \
  pb1_##s = *(const s16x8*)(bgp1 + (size_t)(t) * 256); }

#define GS1(s, t, DOLOAD) { \
  char* buf = lds[(s) & 1]; \
  *(s16x8*)(buf + awo0) = pa0_##s; \
  *(s16x8*)(buf + awo1) = pa1_##s; \
  *(s16x8*)(buf + 16384 + awo0) = pb0_##s; \
  *(s16x8*)(buf + 16384 + awo1) = pb1_##s; \
  asm volatile("s_waitcnt lgkmcnt(0)" ::: "memory"); \
  __builtin_amdgcn_s_barrier(); \
  asm volatile("" ::: "memory"); \
  if (DOLOAD) GI1(s, (t) + 4) \
  __builtin_amdgcn_s_setprio(1); \
  _Pragma("unroll") \
  for (int ks = 0; ks < 4; ++ks) { \
    const int kq = ((ks << 6) | lk) ^ swz; \
    s16x8 a0 = *(const s16x8*)(buf + aoff + kq); \
    s16x8 a1 = *(const s16x8*)(buf + aoff + 4096 + kq); \
    s16x8 b0 = *(const s16x8*)(buf + 16384 + boff + kq); \
    acc0 = __builtin_amdgcn_mfma_f32_16x16x32_bf16(a0, b0, acc0, 0, 0, 0); \
    acc1 = __builtin_amdgcn_mfma_f32_16x16x32_bf16(a1, b0, acc1, 0, 0, 0); \
  } \
  __builtin_amdgcn_s_setprio(0); }

__global__ __launch_bounds__(512) void k_gemm1(
    const u16* __restrict__ A, const u16* __restrict__ B,
    const float* __restrict__ bias, u16* __restrict__ Y,
    const float* __restrict__ W1f, u16* __restrict__ w1b) {
  constexpr int K = 2048, N = 2048;
  if (blockIdx.x >= 256) {  // W1 conversion riders
    const size_t e = (((size_t)blockIdx.x - 256) * 512 + threadIdx.x) * 8;
    f32x4 a = *(const f32x4*)(W1f + e), b2 = *(const f32x4*)(W1f + e + 4);
    *(s16x8*)(w1b + e) = pack8(a, b2);
    return;
  }
  __shared__ char lds[2][32768];  // A 16KB + B 16KB per buffer
  const int tid = threadIdx.x;
  const int w = tid >> 6, l = tid & 63;
  const int wr = w >> 2, wn = w & 3;
  const int lrow = l & 15;
  const int lk = (l >> 4) << 4;
  const int swz = lrow << 4;

  // XCD swizzle (256 GEMM blocks): each XCD owns 32 contiguous wgids (4 bn x 8 bm)
  const int wgid = (blockIdx.x & 7) * 32 + (blockIdx.x >> 3);
  const int bn = wgid >> 3, bm = wgid & 7;

  const size_t K2 = (size_t)K * 2;  // 4096 B/row
  const char* Ag = (const char*)A + (size_t)bm * 64 * K2;
  const char* Bg = (const char*)B + (size_t)bn * 64 * K2;

  // staging: tile 64 rows x 256B; thread covers bytes tid*16 and tid*16+8192
  const int o0 = tid * 16;
  const int ar0 = o0 >> 8, ac0 = o0 & 255;
  const char* agp0 = Ag + (size_t)ar0 * K2 + ac0;
  const char* bgp0 = Bg + (size_t)ar0 * K2 + ac0;
  const int awo0 = (ar0 << 8) + (ac0 ^ ((ar0 & 15) << 4));
  const int o1 = o0 + 8192;
  const int ar1 = o1 >> 8, ac1 = o1 & 255;
  const char* agp1 = Ag + (size_t)ar1 * K2 + ac1;
  const char* bgp1 = Bg + (size_t)ar1 * K2 + ac1;
  const int awo1 = (ar1 << 8) + (ac1 ^ ((ar1 & 15) << 4));

  const int aoff = (wr * 32 + lrow) * 256;
  const int boff = (wn * 16 + lrow) * 256;

  f32x4 acc0 = {}, acc1 = {};
  s16x8 pa0_0, pa0_1, pa0_2, pa0_3;
  s16x8 pa1_0, pa1_1, pa1_2, pa1_3;
  s16x8 pb0_0, pb0_1, pb0_2, pb0_3;
  s16x8 pb1_0, pb1_1, pb1_2, pb1_3;

  GI1(0, 0) GI1(1, 1) GI1(2, 2) GI1(3, 3)
  constexpr int NT = 16;  // K/128
  int t = 0;
  for (; t < NT - 4; t += 4) {
    GS1(0, t, 1) GS1(1, t + 1, 1) GS1(2, t + 2, 1) GS1(3, t + 3, 1)
  }
  GS1(0, t, 0) GS1(1, t + 1, 0) GS1(2, t + 2, 0) GS1(3, t + 3, 0)

  // epilogue: C/D map col=lane&15, row=(lane>>4)*4+reg
  const int colg = bn * 64 + wn * 16 + lrow;
  const int rowb = bm * 64 + wr * 32 + ((l >> 4) << 2);
  const float bv = bias[colg];
#pragma unroll
  for (int fa = 0; fa < 2; ++fa)
#pragma unroll
    for (int r = 0; r < 4; ++r) {
      float v = (fa ? acc1 : acc0)[r] + bv;
      v = v > 0.f ? v : 0.f;
      Y[(size_t)(rowb + fa * 16 + r) * N + colg] = f2bf(v);
    }
}

// ================= K2: gemm2 — 32x64 tile, BK=128, 8 waves, grid 256 ============
#define GI2(s, t) { \
  pa_##s = *(const s16x8*)(agp0 + (size_t)(t) * 256); \
  pb0_##s = *(const s16x8*)(bgp0 + (size_t)(t) * 256); \
  pb1_##s = *(const s16x8*)(bgp1 + (size_t)(t) * 256); }

#define GS2(s, t, DOLOAD) { \
  char* buf = lds[(s) & 1]; \
  *(s16x8*)(buf + awo0) = pa_##s; \
  *(s16x8*)(buf + 8192 + bwo0) = pb0_##s; \
  *(s16x8*)(buf + 8192 + bwo1) = pb1_##s; \
  asm volatile("s_waitcnt lgkmcnt(0)" ::: "memory"); \
  __builtin_amdgcn_s_barrier(); \
  asm volatile("" ::: "memory"); \
  if (DOLOAD) GI2(s, (t) + 4) \
  __builtin_amdgcn_s_setprio(1); \
  _Pragma("unroll") \
  for (int ks = 0; ks < 4; ++ks) { \
    const int kq = ((ks << 6) | lk) ^ swz; \
    s16x8 a0 = *(const s16x8*)(buf + aoff + kq); \
    s16x8 b0 = *(const s16x8*)(buf + 8192 + boff + kq); \
    acc0 = __builtin_amdgcn_mfma_f32_16x16x32_bf16(a0, b0, acc0, 0, 0, 0); \
  } \
  __builtin_amdgcn_s_setprio(0); }

__global__ __launch_bounds__(512) void k_gemm2(
    const u16* __restrict__ A, const u16* __restrict__ B,
    const float* __restrict__ bias, u16* __restrict__ Y) {
  constexpr int K = 2048, N = 1024;
  __shared__ char lds[2][24576];  // A 8KB + B 16KB per buffer
  const int tid = threadIdx.x;
  const int w = tid >> 6, l = tid & 63;
  const int wr = w >> 2, wn = w & 3;
  const int lrow = l & 15;
  const int lk = (l >> 4) << 4;
  const int swz = lrow << 4;

  // XCD swizzle (grid 256): each XCD owns 32 contiguous wgids (2 bn x 16 bm)
  const int wgid = (blockIdx.x & 7) * 32 + (blockIdx.x >> 3);
  const int bn = wgid >> 4, bm = wgid & 15;

  const size_t K2 = (size_t)K * 2;
  const char* Ag = (const char*)A + (size_t)bm * 32 * K2;
  const char* Bg = (const char*)B + (size_t)bn * 64 * K2;

  // A staging: 32 rows x 256B = 8KB; thread covers byte tid*16
  const int o0 = tid * 16;
  const int ar0 = o0 >> 8, ac0 = o0 & 255;
  const char* agp0 = Ag + (size_t)ar0 * K2 + ac0;
  const int awo0 = (ar0 << 8) + (ac0 ^ ((ar0 & 15) << 4));
  // B staging: 64 rows x 256B = 16KB; thread covers bytes tid*16 and +8192
  const char* bgp0 = Bg + (size_t)ar0 * K2 + ac0;
  const int bwo0 = awo0;
  const int o1 = o0 + 8192;
  const int br1 = o1 >> 8, bc1 = o1 & 255;
  const char* bgp1 = Bg + (size_t)br1 * K2 + bc1;
  const int bwo1 = (br1 << 8) + (bc1 ^ ((br1 & 15) << 4));

  const int aoff = (wr * 16 + lrow) * 256;
  const int boff = (wn * 16 + lrow) * 256;

  f32x4 acc0 = {};
  s16x8 pa_0, pa_1, pa_2, pa_3;
  s16x8 pb0_0, pb0_1, pb0_2, pb0_3;
  s16x8 pb1_0, pb1_1, pb1_2, pb1_3;

  GI2(0, 0) GI2(1, 1) GI2(2, 2) GI2(3, 3)
  constexpr int NT = 16;
  int t = 0;
  for (; t < NT - 4; t += 4) {
    GS2(0, t, 1) GS2(1, t + 1, 1) GS2(2, t + 2, 1) GS2(3, t + 3, 1)
  }
  GS2(0, t, 0) GS2(1, t + 1, 0) GS2(2, t + 2, 0) GS2(3, t + 3, 0)

  const int colg = bn * 64 + wn * 16 + lrow;
  const int rowb = bm * 32 + wr * 16 + ((l >> 4) << 2);
  const float bv = bias[colg];
#pragma unroll
  for (int r = 0; r < 4; ++r) {
    float v = acc0[r] + bv;
    v = v > 0.f ? v : 0.f;
    Y[(size_t)(rowb + r) * N + colg] = f2bf(v);
  }
}

// ================= K3: head; atomicAdd partials into out =============
#define H_ISSUE(S, ch) { \
  const float* src = hsrc + (ch) * 256; \
  q0_##S = *(const f32x4*)(src);      q1_##S = *(const f32x4*)(src + 4); \
  q2_##S = *(const f32x4*)(src + 8);  q3_##S = *(const f32x4*)(src + 12); \
  q4_##S = *(const f32x4*)(src + 16); q5_##S = *(const f32x4*)(src + 20); \
  q6_##S = *(const f32x4*)(src + 24); q7_##S = *(const f32x4*)(src + 28); }

#define H_WRITE(S, ch) { \
  char* dst = lbuf[(ch) & 1] + (hrow << 9); \
  *(s16x8*)(dst + ((hcb + 0)  ^ hswz)) = pack8(q0_##S, q1_##S); \
  *(s16x8*)(dst + ((hcb + 16) ^ hswz)) = pack8(q2_##S, q3_##S); \
  *(s16x8*)(dst + ((hcb + 32) ^ hswz)) = pack8(q4_##S, q5_##S); \
  *(s16x8*)(dst + ((hcb + 48) ^ hswz)) = pack8(q6_##S, q7_##S); }

#define H_SYNC { \
  asm volatile("s_waitcnt lgkmcnt(0)" ::: "memory"); \
  __builtin_amdgcn_s_barrier(); \
  asm volatile("" ::: "memory"); }

#define H_MFMA(ch) { \
  const char* bb = lbuf[(ch) & 1]; \
  s16x8 bv0 = *(const s16x8*)(bb + ((0 * 16 + lrow) << 9) + kboff); \
  s16x8 bv1 = *(const s16x8*)(bb + ((1 * 16 + lrow) << 9) + kboff); \
  s16x8 bv2 = *(const s16x8*)(bb + ((2 * 16 + lrow) << 9) + kboff); \
  s16x8 bv3 = *(const s16x8*)(bb + ((3 * 16 + lrow) << 9) + kboff); \
  s16x8 av0 = *(const s16x8*)(ap0 + (ch) * 256); \
  s16x8 av1 = *(const s16x8*)(ap1 + (ch) * 256); \
  __builtin_amdgcn_s_setprio(1); \
  acc[0][0] = __builtin_amdgcn_mfma_f32_16x16x32_bf16(av0, bv0, acc[0][0], 0, 0, 0); \
  acc[0][1] = __builtin_amdgcn_mfma_f32_16x16x32_bf16(av0, bv1, acc[0][1], 0, 0, 0); \
  acc[0][2] = __builtin_amdgcn_mfma_f32_16x16x32_bf16(av0, bv2, acc[0][2], 0, 0, 0); \
  acc[0][3] = __builtin_amdgcn_mfma_f32_16x16x32_bf16(av0, bv3, acc[0][3], 0, 0, 0); \
  acc[1][0] = __builtin_amdgcn_mfma_f32_16x16x32_bf16(av1, bv0, acc[1][0], 0, 0, 0); \
  acc[1][1] = __builtin_amdgcn_mfma_f32_16x16x32_bf16(av1, bv1, acc[1][1], 0, 0, 0); \
  acc[1][2] = __builtin_amdgcn_mfma_f32_16x16x32_bf16(av1, bv2, acc[1][2], 0, 0, 0); \
  acc[1][3] = __builtin_amdgcn_mfma_f32_16x16x32_bf16(av1, bv3, acc[1][3], 0, 0, 0); \
  __builtin_amdgcn_s_setprio(0); }

__global__ __launch_bounds__(512) void k_head(
    const int* __restrict__ cells, const u16* __restrict__ y2b,
    const float* __restrict__ L0, const float* __restrict__ O0,
    const float* __restrict__ L1, float* __restrict__ out) {
  __shared__ int slist[544];
  __shared__ int scnt;
  __shared__ float red[8][2048];      // 64 KB
  __shared__ char lbuf[2][32768];     // 64 KB
  const int tid = threadIdx.x;
  const int c = blockIdx.x >> 3, rt = blockIdx.x & 7;
  if (tid == 0) scnt = 0;
  __syncthreads();
  for (int i = tid; i < BATCH; i += 512)
    if (cells[i] == c) slist[atomicAdd(&scnt, 1)] = i;
  __syncthreads();
  const int ns = scnt;
  if (ns == 0) return;
  const int npad = (ns + 31) & ~31;
  for (int i = ns + tid; i < npad; i += 512) slist[i] = slist[0];
  __syncthreads();

  const int w = tid >> 6, l = tid & 63;
  const int lrow = l & 15;
  const int r0 = rt * 64;
  const float* L0c = L0 + ((size_t)c * N2 + r0) * N1;
  const int hrow = tid >> 3;
  const int hcb = (tid & 7) * 64;
  const int hswz = (hrow & 7) << 4;
  const float* hsrc = L0c + (size_t)hrow * N1 + (tid & 7) * 32;
  const int kboff = ((w * 64 + ((l >> 4) << 4)) ^ ((lrow & 7) << 4));

  f32x4 q0_A, q1_A, q2_A, q3_A, q4_A, q5_A, q6_A, q7_A;
  f32x4 q0_B, q1_B, q2_B, q3_B, q4_B, q5_B, q6_B, q7_B;

  for (int cb = 0; cb < npad; cb += 32) {
    const u16* ap0 = y2b + (size_t)slist[cb + lrow] * N1 + w * 32 + ((l >> 4) << 3);
    const u16* ap1 = y2b + (size_t)slist[cb + 16 + lrow] * N1 + w * 32 + ((l >> 4) << 3);
    f32x4 acc[2][4] = {};
    H_ISSUE(A, 0)
    H_WRITE(A, 0)
    H_ISSUE(B, 1)
    H_SYNC
    H_MFMA(0)
    H_WRITE(B, 1)
    H_ISSUE(A, 2)
    H_SYNC
    H_MFMA(1)
    H_WRITE(A, 2)
    H_ISSUE(B, 3)
    H_SYNC
    H_MFMA(2)
    H_WRITE(B, 3)
    H_SYNC
    H_MFMA(3)

    __syncthreads();
#pragma unroll
    for (int h = 0; h < 2; ++h)
#pragma unroll
      for (int fb = 0; fb < 4; ++fb)
#pragma unroll
        for (int r = 0; r < 4; ++r) {
          const int s0 = h * 16 + (l >> 4) * 4 + r;
          red[w][s0 * 64 + fb * 16 + lrow] = acc[h][fb][r];
        }
    __syncthreads();
    {
      const int s = tid >> 4;
      const int rq = (tid & 15) * 4;
      if (cb + s < ns) {
        float p = 0.f;
#pragma unroll
        for (int j = 0; j < 4; ++j) {
          const int r = rq + j, e = s * 64 + r;
          float v = red[0][e] + red[1][e] + red[2][e] + red[3][e] +
                    red[4][e] + red[5][e] + red[6][e] + red[7][e] +
                    O0[(size_t)c * N2 + r0 + r];
          v = v > 0.f ? v : 0.f;
          p += v * L1[(size_t)c * N2 + r0 + r];
        }
#pragma unroll
        for (int off = 8; off; off >>= 1) p += __shfl_xor(p, off, 16);
        if ((tid & 15) == 0) atomicAdd(&out[slist[cb + s]], p);
      }
    }
  }
}

// ---------------- launch ----------------
extern "C" void kernel_launch(void* const* d_in, const int* in_sizes, int n_in,
                              void* d_out, int out_size, void* d_ws, size_t ws_size,
                              hipStream_t stream) {
  const int*   pairs  = (const int*)d_in[0];
  const int*   cells  = (const int*)d_in[1];
  const float* attrs  = (const float*)d_in[2];
  const float* h_drug = (const float*)d_in[3];
  const float* W0     = (const float*)d_in[4];
  const float* b0     = (const float*)d_in[5];
  const float* W1     = (const float*)d_in[6];
  const float* b1     = (const float*)d_in[7];
  const float* L0     = (const float*)d_in[8];
  const float* O0     = (const float*)d_in[9];
  const float* L1     = (const float*)d_in[10];
  const float* O1     = (const float*)d_in[11];
  float* out = (float*)d_out;

  char* ws = (char*)d_ws;
  u16* xb  = (u16*)(ws);                  // 2 MB  512x2048 bf16
  u16* w0b = (u16*)(ws + (2u  << 20));    // 8 MB  2048x2048 bf16
  u16* w1b = (u16*)(ws + (10u << 20));    // 4 MB  1024x2048 bf16
  u16* y1b = (u16*)(ws + (14u << 20));    // 2 MB  512x2048 bf16
  u16* y2b = (u16*)(ws + (16u << 20));    // 1 MB  512x1024 bf16

  k_prep<<<1536, 256, 0, stream>>>(pairs, attrs, h_drug, W0, cells, O1,
                                   xb, w0b, out);
  k_gemm1<<<768, 512, 0, stream>>>(xb, w0b, b0, y1b, W1, w1b);
  k_gemm2<<<256, 512, 0, stream>>>(y1b, w1b, b1, y2b);
  k_head<<<256, 512, 0, stream>>>(cells, y2b, L0, O0, L1, out);
}